// Round 13
// baseline (522.838 us; speedup 1.0000x reference)
//
#include <hip/hip_runtime.h>
#include <math.h>

#define BATCH 65536
#define LEAD  24
#define MEM   51
#define NPRED 6
#define HID   128
#define TB    64
#define NBLK  4
#define OUTC  960

#define HSTR  136            // bf16 plane stride
#define HPL   (64 * HSTR)    // elements per plane
#define CSTR  165            // f32 C-stage stride (fused fallback only)

// d_ws layout:
//   [0, 786432)                      prepped weights (ushort), fragment-major (round-11 layout)
//   [786432, 786432 + 251658240)     Y stage: f32 [BATCH][960]  (split path only)
#define WS_USHORTS 393216
#define WS_BYTES   786432
#define Y_BYTES    ((size_t)BATCH * OUTC * 4)
#define WS_TOTAL   ((size_t)WS_BYTES + Y_BYTES)

typedef float f32x4 __attribute__((ext_vector_type(4)));
typedef short s16x8 __attribute__((ext_vector_type(8)));

__device__ __forceinline__ float sp_softplus(float z) {
    return fmaxf(z, 0.0f) + log1pf(expf(-fabsf(z)));
}
__device__ __forceinline__ float silu_f(float z) {
    return z / (1.0f + expf(-z));
}
__device__ __forceinline__ void bf16split(float x, unsigned &hi, unsigned &lo) {
    unsigned xb = __float_as_uint(x);
    hi = xb >> 16;
    float fhi = __uint_as_float(xb & 0xFFFF0000u);
    lo = __float_as_uint(x - fhi) >> 16;
}
__device__ __forceinline__ float bf16re(short u) {
    return __uint_as_float(((unsigned)(unsigned short)u) << 16);
}

// ---------------- prep: transpose + hi/lo split into FRAGMENT-MAJOR order ----------------
__global__ __launch_bounds__(256) void prep_kernel(
    const float* __restrict__ W_in,
    const float* __restrict__ Ws0, const float* __restrict__ Ws1,
    const float* __restrict__ Ws2, const float* __restrict__ Ws3,
    const float* __restrict__ W_out, unsigned short* __restrict__ wq)
{
    int idx = blockIdx.x * 256 + threadIdx.x;   // 0..196607
    float val; int ih, il;
    if (idx < 8192) {                  // W_inT: tile(8) x kt(2) x lane(64) x j(8)
        int tile = idx >> 10, rem = idx & 1023;
        int kk = rem >> 9, lane = (rem >> 3) & 63, j = rem & 7;
        int col = tile * 16 + (lane & 15);
        int k   = kk * 32 + (lane >> 4) * 8 + j;
        val = (k < 54) ? W_in[k * HID + col] : 0.0f;
        ih = idx; il = 8192 + idx;
    } else if (idx < 73728) {          // WsT: 4 layers x tile(8) x kt(4) x lane x j
        int r = idx - 8192, l = r >> 14, r2 = r & 16383;
        int tile = r2 >> 11, rem = r2 & 2047;
        int kk = rem >> 9, lane = (rem >> 3) & 63, j = rem & 7;
        int col = tile * 16 + (lane & 15);
        int k   = kk * 32 + (lane >> 4) * 8 + j;
        const float* W = (l == 0) ? Ws0 : (l == 1) ? Ws1 : (l == 2) ? Ws2 : Ws3;
        val = W[k * HID + col];
        ih = 16384 + l * 32768 + r2; il = ih + 16384;
    } else {                           // W_outT: tile(60) x kt(4) x lane x j
        int r = idx - 73728;
        int tile = r >> 11, rem = r & 2047;
        int kk = rem >> 9, lane = (rem >> 3) & 63, j = rem & 7;
        int col = tile * 16 + (lane & 15);
        int k   = kk * 32 + (lane >> 4) * 8 + j;
        val = W_out[k * OUTC + col];
        ih = 147456 + r; il = 270336 + r;
    }
    unsigned hi, lo; bf16split(val, hi, lo);
    wq[ih] = (unsigned short)hi;
    wq[il] = (unsigned short)lo;
}

// ---------------- writeback: acc -> silu(+skip) -> split bf16 planes ----------------
template<bool SKIP>
__device__ __forceinline__ void writeback(f32x4 (&acc)[4][2], short* hpl,
                                          const float* __restrict__ bias,
                                          int w, int lL, int lH) {
    const bool evn = (lL & 1) == 0;
    unsigned* u32p = (unsigned*)hpl;
    #pragma unroll
    for (int n = 0; n < 2; ++n) {
        const int colb = w * 32 + n * 16 + lL;
        const float bv = bias[colb];
        #pragma unroll
        for (int m = 0; m < 4; ++m) {
            #pragma unroll
            for (int r = 0; r < 4; ++r) {
                const int row = m * 16 + lH * 4 + r;
                float v = acc[m][n][r] + bv;
                float hnew;
                if (SKIP) {
                    float ho = bf16re(hpl[row * HSTR + colb]) + bf16re(hpl[HPL + row * HSTR + colb]);
                    hnew = silu_f(v) + ho;
                } else {
                    hnew = silu_f(v);
                }
                unsigned hi, lo; bf16split(hnew, hi, lo);
                unsigned phi = (unsigned)__shfl_xor((int)hi, 1);
                unsigned plo = (unsigned)__shfl_xor((int)lo, 1);
                if (evn) {
                    u32p[(row * HSTR + colb) >> 1]       = hi | (phi << 16);
                    u32p[(HPL + row * HSTR + colb) >> 1] = lo | (plo << 16);
                }
            }
        }
    }
}

#define MFMA(a, b, c) __builtin_amdgcn_mfma_f32_16x16x32_bf16((a), (b), (c), 0, 0, 0)

// ---------------- shared device body: phases 0-2 (stats + MLP into hpl) ----------------
__device__ __forceinline__ void mlp_phases(
    const float* __restrict__ x, const float* __restrict__ p,
    const float* __restrict__ b_in,
    const float* __restrict__ bs0, const float* __restrict__ bs1,
    const float* __restrict__ bs2, const float* __restrict__ bs3,
    const unsigned short* __restrict__ wq,
    short* hpl, int t, int lane, int w, int lL, int lH, int b0)
{
    // -------- phase 0: stats -> split-bf16 input planes --------
    {
        const int grp = lane >> 4, sub = lane & 15;
        for (int it = 0; it < (TB * LEAD) / 16; ++it) {
            int rowl = it * 16 + w * 4 + grp;
            const float* xr = x + (size_t)(b0 * LEAD + rowl) * MEM;
            float v0 = xr[sub], v1 = xr[sub + 16], v2 = xr[sub + 32];
            float v3 = (sub < 3) ? xr[sub + 48] : 0.0f;
            float sum = v0 + v1 + v2 + v3;
            float ss  = v0 * v0 + v1 * v1 + v2 * v2 + v3 * v3;
            sum += __shfl_xor(sum, 1);  ss += __shfl_xor(ss, 1);
            sum += __shfl_xor(sum, 2);  ss += __shfl_xor(ss, 2);
            sum += __shfl_xor(sum, 4);  ss += __shfl_xor(ss, 4);
            sum += __shfl_xor(sum, 8);  ss += __shfl_xor(ss, 8);
            if (sub == 0) {
                int bl = rowl / LEAD, ld = rowl - bl * LEAD;
                float mv = sum / 51.0f;
                float sd = sqrtf(fmaxf((ss - 51.0f * mv * mv) / 50.0f, 0.0f));
                unsigned hi, lo;
                bf16split(mv, hi, lo);
                hpl[bl * HSTR + 2 * ld] = (short)hi;  hpl[HPL + bl * HSTR + 2 * ld] = (short)lo;
                bf16split(sd, hi, lo);
                hpl[bl * HSTR + 2 * ld + 1] = (short)hi;  hpl[HPL + bl * HSTR + 2 * ld + 1] = (short)lo;
            }
        }
        for (int idx = t; idx < TB * NPRED; idx += 256) {
            int bl = idx / NPRED, j = idx - bl * NPRED;
            unsigned hi, lo;
            bf16split(p[(size_t)(b0 + bl) * NPRED + j], hi, lo);
            hpl[bl * HSTR + 48 + j] = (short)hi;  hpl[HPL + bl * HSTR + 48 + j] = (short)lo;
        }
        {
            int row = t >> 2;
            unsigned* u32p = (unsigned*)hpl;
            for (int c2 = 54 + 2 * (t & 3); c2 < 64; c2 += 8) {
                u32p[(row * HSTR + c2) >> 1] = 0u;
                u32p[(HPL + row * HSTR + c2) >> 1] = 0u;
            }
        }
    }
    __syncthreads();

    // -------- phase 1: input layer GEMM, K=64, 3-pass split --------
    {
        f32x4 acc[4][2];
        #pragma unroll
        for (int m = 0; m < 4; ++m)
            #pragma unroll
            for (int n = 0; n < 2; ++n) acc[m][n] = (f32x4){0.f, 0.f, 0.f, 0.f};
        #pragma unroll
        for (int n = 0; n < 2; ++n) {
            const int tile = w * 2 + n;
            #pragma unroll
            for (int kk = 0; kk < 2; ++kk) {
                const unsigned short* bp_ = wq + ((tile * 2 + kk) * 64 + lane) * 8;
                s16x8 bh = *(const s16x8*)bp_;
                s16x8 bl = *(const s16x8*)(bp_ + 8192);
                #pragma unroll
                for (int m = 0; m < 4; ++m) {
                    const short* ap = &hpl[(m * 16 + lL) * HSTR + kk * 32 + lH * 8];
                    s16x8 ah = *(const s16x8*)ap;
                    s16x8 al = *(const s16x8*)(ap + HPL);
                    acc[m][n] = MFMA(ah, bh, acc[m][n]);
                    acc[m][n] = MFMA(ah, bl, acc[m][n]);
                    acc[m][n] = MFMA(al, bh, acc[m][n]);
                }
            }
        }
        __syncthreads();
        writeback<false>(acc, hpl, b_in, w, lL, lH);
    }
    __syncthreads();

    // -------- phase 2: 4 skip layers, K=128 --------
    {
        const float* bsp[4] = {bs0, bs1, bs2, bs3};
        #pragma unroll 1
        for (int L = 0; L < 4; ++L) {
            const unsigned short* wsl = wq + 16384 + L * 32768;
            const float* bp = bsp[L];
            f32x4 acc[4][2];
            #pragma unroll
            for (int m = 0; m < 4; ++m)
                #pragma unroll
                for (int n = 0; n < 2; ++n) acc[m][n] = (f32x4){0.f, 0.f, 0.f, 0.f};
            #pragma unroll
            for (int n = 0; n < 2; ++n) {
                const int tile = w * 2 + n;
                #pragma unroll
                for (int kk = 0; kk < 4; ++kk) {
                    const unsigned short* bp_ = wsl + ((tile * 4 + kk) * 64 + lane) * 8;
                    s16x8 bh = *(const s16x8*)bp_;
                    s16x8 bl = *(const s16x8*)(bp_ + 16384);
                    #pragma unroll
                    for (int m = 0; m < 4; ++m) {
                        const short* ap = &hpl[(m * 16 + lL) * HSTR + kk * 32 + lH * 8];
                        s16x8 ah = *(const s16x8*)ap;
                        s16x8 al = *(const s16x8*)(ap + HPL);
                        acc[m][n] = MFMA(ah, bh, acc[m][n]);
                        acc[m][n] = MFMA(ah, bl, acc[m][n]);
                        acc[m][n] = MFMA(al, bh, acc[m][n]);
                    }
                }
            }
            __syncthreads();
            writeback<true>(acc, hpl, bp, w, lL, lH);
            __syncthreads();
        }
    }
}

// ---------------- split-path GEMM kernel: phases 0-2 + out-layer -> Y (global) ----------------
__global__ __launch_bounds__(256, 4) void gemm_kernel(
    const float* __restrict__ x, const float* __restrict__ p,
    const float* __restrict__ b_in,
    const float* __restrict__ bs0, const float* __restrict__ bs1,
    const float* __restrict__ bs2, const float* __restrict__ bs3,
    const float* __restrict__ b_out,
    const unsigned short* __restrict__ wq,
    float* __restrict__ Y)
{
    __shared__ short hpl[2 * HPL];   // 34816 B only -> 4 blocks/CU

    const int t    = threadIdx.x;
    const int lane = t & 63;
    const int w    = t >> 6;
    const int lL   = lane & 15;
    const int lH   = lane >> 4;
    const int b0   = blockIdx.x * TB;

    mlp_phases(x, p, b_in, bs0, bs1, bs2, bs3, wq, hpl, t, lane, w, lL, lH, b0);

    // -------- phase 3: out layer, M-split by wave, A-frags hoisted to registers --------
    const unsigned short* wop = wq + 147456;
    s16x8 ah[4], al[4];
    #pragma unroll
    for (int kk = 0; kk < 4; ++kk) {
        const short* ap = &hpl[(w * 16 + lL) * HSTR + kk * 32 + lH * 8];
        ah[kk] = *(const s16x8*)ap;
        al[kk] = *(const s16x8*)(ap + HPL);
    }
    float* yb = Y + (size_t)b0 * OUTC;
    #pragma unroll 2
    for (int nt = 0; nt < 60; ++nt) {
        f32x4 d = {0.f, 0.f, 0.f, 0.f};
        #pragma unroll
        for (int kk = 0; kk < 4; ++kk) {
            const unsigned short* bp_ = wop + ((nt * 4 + kk) * 64 + lane) * 8;
            s16x8 bh = *(const s16x8*)bp_;
            s16x8 bl = *(const s16x8*)(bp_ + 122880);
            d = MFMA(ah[kk], bh, d);
            d = MFMA(ah[kk], bl, d);
            d = MFMA(al[kk], bh, d);
        }
        const int col = nt * 16 + lL;
        const float bv = b_out[col];
        #pragma unroll
        for (int r = 0; r < 4; ++r) {
            const int row = w * 16 + lH * 4 + r;
            yb[(size_t)row * OUTC + col] = d[r] + bv;   // 16-lane 64B segments
        }
    }
}

// ---------------- split-path spline kernel: 1 thread = 1 (b,lead) ----------------
__global__ __launch_bounds__(256, 4) void spline_kernel(
    const float* __restrict__ Y, const float* __restrict__ f,
    float* __restrict__ out)
{
    const int idx = blockIdx.x * 256 + threadIdx.x;     // 0 .. BATCH*LEAD-1
    const int b   = idx / LEAD;
    const int l   = idx - b * LEAD;

    float cc[40];
    const f32x4* yp = (const f32x4*)(Y + (size_t)b * OUTC + l * 40);
    #pragma unroll
    for (int v = 0; v < 10; ++v) {
        f32x4 q = yp[v];
        cc[4 * v + 0] = q[0]; cc[4 * v + 1] = q[1];
        cc[4 * v + 2] = q[2]; cc[4 * v + 3] = q[3];
    }

    float ff = f[idx];
    float dt_prod = 1.0f;
    #pragma unroll
    for (int blk = 0; blk < NBLK; ++blk) {
        float tk[5], yk[5];
        tk[0] = cc[blk * 10 + 0];
        yk[0] = cc[blk * 10 + 5];
        #pragma unroll
        for (int kk = 1; kk < 5; ++kk) {
            tk[kk] = tk[kk - 1] + 0.001f + sp_softplus(cc[blk * 10 + kk]);
            yk[kk] = yk[kk - 1] + 0.001f + sp_softplus(cc[blk * 10 + 5 + kk]);
        }
        float df[4];
        #pragma unroll
        for (int j = 0; j < 4; ++j) df[j] = (yk[j + 1] - yk[j]) / (tk[j + 1] - tk[j]);
        float g02 = (yk[2] - yk[0]) / (tk[2] - tk[0]);
        float g13 = (yk[3] - yk[1]) / (tk[3] - tk[1]);
        float g24 = (yk[4] - yk[2]) / (tk[4] - tk[2]);
        float dd[5];
        dd[0] = df[0] * df[0] / g02;
        dd[1] = df[0] * df[1] / g02;
        dd[2] = df[1] * df[2] / g13;
        dd[3] = df[2] * df[3] / g24;
        dd[4] = df[3] * df[3] / g24;

        int cnt = (ff > tk[0]) + (ff > tk[1]) + (ff > tk[2]) + (ff > tk[3]) + (ff > tk[4]);
        bool e0 = (cnt == 0), e1 = (cnt == 5);
        int k0 = cnt - 1; k0 = k0 < 0 ? 0 : (k0 > 3 ? 3 : k0);

        float t0v = tk[0], t1v = tk[1], y0v = yk[0], y1v = yk[1], d0v = dd[0], d1v = dd[1];
        #pragma unroll
        for (int j = 1; j < 4; ++j) {
            bool c = (k0 == j);
            t0v = c ? tk[j] : t0v;  t1v = c ? tk[j + 1] : t1v;
            y0v = c ? yk[j] : y0v;  y1v = c ? yk[j + 1] : y1v;
            d0v = c ? dd[j] : d0v;  d1v = c ? dd[j + 1] : d1v;
        }

        float dt_ = t1v - t0v, dy_ = y1v - y0v;
        float s_  = dy_ / dt_;
        float e   = (ff - t0v) / dt_;
        float one_e = 1.0f - e;
        float bb  = d1v + d0v - 2.0f * s_;
        float n0  = dy_ * (s_ * e * e + d0v * e * one_e);
        float n1  = s_ + bb * e * one_e;
        float p_mid = y0v + n0 / n1;
        float p_lo  = d0v * ff + (y0v - d0v * t0v);
        float p_hi  = d1v * ff + (y1v - d1v * t1v);
        float val = e0 ? p_lo : (e1 ? p_hi : p_mid);

        float div0 = s_ * s_ * (d1v * e * e + 2.0f * s_ * e * one_e + d0v * one_e * one_e);
        float div1 = n1 * n1;
        float der  = e0 ? d0v : (e1 ? d1v : div0 / div1);

        dt_prod *= der;
        ff = val;
    }
    out[idx] = expf(-0.5f * ff * ff) * dt_prod / 2.5066282746310002f;
}

// ---------------- fused fallback (round-11 kernel, used if ws < WS_TOTAL) ----------------
__global__ __launch_bounds__(256, 2) void fused_mfma_kernel(
    const float* __restrict__ x, const float* __restrict__ p, const float* __restrict__ f,
    const float* __restrict__ b_in,
    const float* __restrict__ bs0, const float* __restrict__ bs1,
    const float* __restrict__ bs2, const float* __restrict__ bs3,
    const float* __restrict__ b_out,
    const unsigned short* __restrict__ wq,
    float* __restrict__ out)
{
    __shared__ short hpl[2 * HPL];
    __shared__ float cbuf[64 * CSTR];

    const int t    = threadIdx.x;
    const int lane = t & 63;
    const int w    = t >> 6;
    const int lL   = lane & 15;
    const int lH   = lane >> 4;
    const int b0   = blockIdx.x * TB;

    mlp_phases(x, p, b_in, bs0, bs1, bs2, bs3, wq, hpl, t, lane, w, lL, lH, b0);

    const unsigned short* wop = wq + 147456;
    #pragma unroll 1
    for (int g = 0; g < 6; ++g) {
        #pragma unroll 1
        for (int nt = 0; nt < 10; ++nt) {
            const int colg = g * 160 + nt * 16 + lL;
            f32x4 d = {0.f, 0.f, 0.f, 0.f};
            #pragma unroll
            for (int kk = 0; kk < 4; ++kk) {
                const unsigned short* bp_ = wop + (((g * 10 + nt) * 4 + kk) * 64 + lane) * 8;
                s16x8 bh = *(const s16x8*)bp_;
                s16x8 bl = *(const s16x8*)(bp_ + 122880);
                const short* ap = &hpl[(w * 16 + lL) * HSTR + kk * 32 + lH * 8];
                s16x8 ah = *(const s16x8*)ap;
                s16x8 al = *(const s16x8*)(ap + HPL);
                d = MFMA(ah, bh, d);
                d = MFMA(ah, bl, d);
                d = MFMA(al, bh, d);
            }
            const float bv = b_out[colg];
            #pragma unroll
            for (int r = 0; r < 4; ++r)
                cbuf[(w * 16 + lH * 4 + r) * CSTR + nt * 16 + lL] = d[r] + bv;
        }
        __syncthreads();

        {
            const int b = t & 63, l = t >> 6;
            const float* cc = &cbuf[b * CSTR + l * 40];
            float ff = f[(size_t)(b0 + b) * LEAD + g * 4 + l];
            float dt_prod = 1.0f;
            #pragma unroll
            for (int blk = 0; blk < NBLK; ++blk) {
                float tk[5], yk[5];
                tk[0] = cc[blk * 10 + 0];
                yk[0] = cc[blk * 10 + 5];
                #pragma unroll
                for (int kk = 1; kk < 5; ++kk) {
                    tk[kk] = tk[kk - 1] + 0.001f + sp_softplus(cc[blk * 10 + kk]);
                    yk[kk] = yk[kk - 1] + 0.001f + sp_softplus(cc[blk * 10 + 5 + kk]);
                }
                float df[4];
                #pragma unroll
                for (int j = 0; j < 4; ++j) df[j] = (yk[j + 1] - yk[j]) / (tk[j + 1] - tk[j]);
                float g02 = (yk[2] - yk[0]) / (tk[2] - tk[0]);
                float g13 = (yk[3] - yk[1]) / (tk[3] - tk[1]);
                float g24 = (yk[4] - yk[2]) / (tk[4] - tk[2]);
                float dd[5];
                dd[0] = df[0] * df[0] / g02;
                dd[1] = df[0] * df[1] / g02;
                dd[2] = df[1] * df[2] / g13;
                dd[3] = df[2] * df[3] / g24;
                dd[4] = df[3] * df[3] / g24;

                int cnt = (ff > tk[0]) + (ff > tk[1]) + (ff > tk[2]) + (ff > tk[3]) + (ff > tk[4]);
                bool e0 = (cnt == 0), e1 = (cnt == 5);
                int k0 = cnt - 1; k0 = k0 < 0 ? 0 : (k0 > 3 ? 3 : k0);

                float t0v = tk[0], t1v = tk[1], y0v = yk[0], y1v = yk[1], d0v = dd[0], d1v = dd[1];
                #pragma unroll
                for (int j = 1; j < 4; ++j) {
                    bool c = (k0 == j);
                    t0v = c ? tk[j] : t0v;  t1v = c ? tk[j + 1] : t1v;
                    y0v = c ? yk[j] : y0v;  y1v = c ? yk[j + 1] : y1v;
                    d0v = c ? dd[j] : d0v;  d1v = c ? dd[j + 1] : d1v;
                }

                float dt_ = t1v - t0v, dy_ = y1v - y0v;
                float s_  = dy_ / dt_;
                float e   = (ff - t0v) / dt_;
                float one_e = 1.0f - e;
                float bb  = d1v + d0v - 2.0f * s_;
                float n0  = dy_ * (s_ * e * e + d0v * e * one_e);
                float n1  = s_ + bb * e * one_e;
                float p_mid = y0v + n0 / n1;
                float p_lo  = d0v * ff + (y0v - d0v * t0v);
                float p_hi  = d1v * ff + (y1v - d1v * t1v);
                float val = e0 ? p_lo : (e1 ? p_hi : p_mid);

                float div0 = s_ * s_ * (d1v * e * e + 2.0f * s_ * e * one_e + d0v * one_e * one_e);
                float div1 = n1 * n1;
                float der  = e0 ? d0v : (e1 ? d1v : div0 / div1);

                dt_prod *= der;
                ff = val;
            }
            out[(size_t)(b0 + b) * LEAD + g * 4 + l] =
                expf(-0.5f * ff * ff) * dt_prod / 2.5066282746310002f;
        }
        __syncthreads();
    }
}

extern "C" void kernel_launch(void* const* d_in, const int* in_sizes, int n_in,
                              void* d_out, int out_size, void* d_ws, size_t ws_size,
                              hipStream_t stream) {
    const float* x     = (const float*)d_in[0];
    const float* p     = (const float*)d_in[1];
    const float* f     = (const float*)d_in[2];
    const float* W_in  = (const float*)d_in[3];
    const float* b_in  = (const float*)d_in[4];
    const float* Ws0   = (const float*)d_in[5];
    const float* bs0   = (const float*)d_in[6];
    const float* Ws1   = (const float*)d_in[7];
    const float* bs1   = (const float*)d_in[8];
    const float* Ws2   = (const float*)d_in[9];
    const float* bs2   = (const float*)d_in[10];
    const float* Ws3   = (const float*)d_in[11];
    const float* bs3   = (const float*)d_in[12];
    const float* W_out = (const float*)d_in[13];
    const float* b_out = (const float*)d_in[14];
    float* out = (float*)d_out;

    if (ws_size >= WS_TOTAL) {
        unsigned short* wq = (unsigned short*)d_ws;
        float* Y = (float*)((char*)d_ws + WS_BYTES);
        prep_kernel<<<768, 256, 0, stream>>>(W_in, Ws0, Ws1, Ws2, Ws3, W_out, wq);
        gemm_kernel<<<BATCH / TB, 256, 0, stream>>>(
            x, p, b_in, bs0, bs1, bs2, bs3, b_out, wq, Y);
        spline_kernel<<<(BATCH * LEAD) / 256, 256, 0, stream>>>(Y, f, out);
    } else if (ws_size >= (size_t)WS_BYTES) {
        unsigned short* wq = (unsigned short*)d_ws;
        prep_kernel<<<768, 256, 0, stream>>>(W_in, Ws0, Ws1, Ws2, Ws3, W_out, wq);
        fused_mfma_kernel<<<BATCH / TB, 256, 0, stream>>>(
            x, p, f, b_in, bs0, bs1, bs2, bs3, b_out, wq, out);
    }
    // (harness guarantees ws; if neither branch taken, output stays poisoned and
    //  the failure is diagnosable as ws_size < 786 KB)
}